// Round 6
// baseline (946.008 us; speedup 1.0000x reference)
//
#include <hip/hip_runtime.h>
#include <hip/hip_bf16.h>

#define L_SEQ 512
#define BATCH 8
#define ND 1024
#define VOCAB_N 32000
#define MROWS 4096   // L*B
#define KDIM 1024
#define BK 64
#define NKT (KDIM / BK)   // 16 K-tiles (layer GEMMs)
#define NKS 32            // KDIM/32 K-steps (output GEMM)
#define NSCAN 128

typedef unsigned short u16;
typedef unsigned int u32;
using bf16x8 = __attribute__((ext_vector_type(8))) __bf16;
using f32x4  = __attribute__((ext_vector_type(4))) float;
using u16x8  = __attribute__((ext_vector_type(8))) unsigned short;
using u16x4  = __attribute__((ext_vector_type(4))) unsigned short;

#define BAR() asm volatile("s_barrier" ::: "memory")
#define VMW(n) asm volatile("s_waitcnt vmcnt(" #n ")" ::: "memory")
#define SCHED() __builtin_amdgcn_sched_barrier(0)

static __device__ __forceinline__ u16 f2bf(float f) {
  u32 u = __builtin_bit_cast(u32, f);
  u32 r = u + 0x7FFF + ((u >> 16) & 1);   // RNE
  return (u16)(r >> 16);
}
static __device__ __forceinline__ float bf2f(u16 b) {
  u32 u = ((u32)b) << 16;
  return __builtin_bit_cast(float, u);
}
static __device__ __forceinline__ void gload16(const void* g, void* l) {
  __builtin_amdgcn_global_load_lds(
      (const __attribute__((address_space(1))) void*)g,
      (__attribute__((address_space(3))) void*)l, 16, 0, 0);
}

// shared transpose-block body: 256 threads, 32x32 tile, W f32[K][N] -> Wt bf16[N][K]
static __device__ __forceinline__ void transpose_body(int tb, const float* __restrict__ W,
                                                      u16* __restrict__ Wt, int Ndim) {
  __shared__ float s[32][33];
  int nx = Ndim >> 5;
  int n0 = (tb % nx) * 32, k0 = (tb / nx) * 32;
  int tid = threadIdx.x;
  int tx = tid & 31, ty = tid >> 5;   // 32 x 8
#pragma unroll
  for (int i = 0; i < 4; i++)
    s[ty * 4 + i][tx] = __builtin_nontemporal_load(
        &W[(size_t)(k0 + ty * 4 + i) * Ndim + n0 + tx]);
  __syncthreads();
  int n = tid >> 3, kg = tid & 7;
  u16x4 o;
#pragma unroll
  for (int j = 0; j < 4; j++) o[j] = f2bf(s[kg * 4 + j][n]);
  *(u16x4*)(Wt + (size_t)(n0 + n) * KDIM + k0 + kg * 4) = o;
}

// ---------------- embedding gather + cast, fused with W0 transpose ----------------
__global__ __launch_bounds__(256) void k_embed_t(const int* __restrict__ x,
                                                 const float* __restrict__ emb,
                                                 u16* __restrict__ h,
                                                 const float* __restrict__ Wsrc,
                                                 u16* __restrict__ WtOut, int NdimT) {
  if (blockIdx.x >= 2048) {
    transpose_body(blockIdx.x - 2048, Wsrc, WtOut, NdimT);
    return;
  }
  int t = blockIdx.x * 256 + threadIdx.x;
  int fidx = t * 8;
  int row = fidx >> 10;
  int col = fidx & 1023;
  int tok = x[row];
  const float4* src = (const float4*)(emb + (size_t)tok * ND + col);
  float4 a = src[0], b = src[1];
  u16x8 o;
  o[0]=f2bf(a.x); o[1]=f2bf(a.y); o[2]=f2bf(a.z); o[3]=f2bf(a.w);
  o[4]=f2bf(b.x); o[5]=f2bf(b.y); o[6]=f2bf(b.z); o[7]=f2bf(b.w);
  *(u16x8*)(h + fidx) = o;
}

// ---------------- standalone transpose (fallback path) ----------------
__global__ __launch_bounds__(256) void k_transpose_cast(const float* __restrict__ W,
                                                        u16* __restrict__ Wt, int Ndim) {
  transpose_body(blockIdx.x, W, Wt, Ndim);
}

// 256-thread staging of an 8 KB chunk (BK=64 swizzled layout, layer GEMMs)
static __device__ __forceinline__ void stage8k(const u16* __restrict__ gbase,
                                               char* sm, int qdst, int tid) {
#pragma unroll
  for (int j = 0; j < 2; ++j) {
    int d = (j * 256 + tid) * 16;
    int o = d ^ (((d >> 7) & 7) << 4);
    gload16(gbase + (size_t)(o >> 7) * KDIM + ((o & 127) >> 1), sm + qdst + d);
  }
}

// swizzled fragment read (BK=64 layout): r = row (A) / col (B), cb = k-byte off
static __device__ __forceinline__ bf16x8 frag_ld(const char* sm, int base, int r, int cb) {
  int p = (r * 128 + cb) ^ ((r & 7) << 4);
  return *(const bf16x8*)(sm + base + p);
}

// BK=32 layout (64 B rows): physical = logical ^ (((o>>7)&3)<<4)
// -> spreads 16 consecutive rows at fixed k-offset over all 8 bank-groups, 2 deep (free).
static __device__ __forceinline__ bf16x8 frag32(const char* smbase, int r, int cb) {
  int p = r * 64 + cb;
  p ^= ((p >> 7) & 3) << 4;
  return *(const bf16x8*)(smbase + p);
}

// ---------------- 128x256 bf16 MFMA GEMM (output projection) ----------------
// 512 threads / 8 waves (2m x 4n), BK=32, 2 blocks/CU.
// A fragments read DIRECTLY from global (XCD-L2-resident via the work map) --
// A never touches LDS. B staged via 4-deep LDS ring (4 x 16 KB), stage t+3,
// counted vmcnt. Halves LDS read traffic (the r0-r4 structural bottleneck).
// Work map: XCD x owns bm in {4x..4x+3} (1 MB of A, L2-hot), sweeps bn.
__global__ __launch_bounds__(512, 4) void k_gemm_out(const u16* __restrict__ A,
                                                     const u16* __restrict__ Bt,
                                                     float* __restrict__ CoutF, int Ndim,
                                                     const float* __restrict__ bias) {
  extern __shared__ __align__(16) char sm[];   // 4 x B-buf 16 KB = 65536

  int bid = blockIdx.x;
  int xcd = bid & 7;                 // dispatch round-robin across 8 XCDs
  int i = bid >> 3;                  // 0..499 local index within XCD
  int bm = (xcd << 2) | (i & 3);     // XCD owns 4 consecutive A panels (1 MB)
  int bn = i >> 2;                   // bn-major sweep: 4 same-bn blocks concurrent
  int m0 = bm * 128, n0 = bn * 256;

  int tid = threadIdx.x;
  int lane = tid & 63, w = tid >> 6;      // 8 waves
  int wm = w >> 2, wn = w & 3;            // 2 x 4; wave owns rows wm*64+[0,64), cols wn*64+[0,64)
  int l15 = lane & 15, hi16 = lane >> 4;

  f32x4 acc[4][4] = {};
  bf16x8 aA[4], bB[2];

  const u16* Bb = Bt + (size_t)n0 * KDIM;
  // per-lane A fragment base: row = m0 + wm*64 + l15, k-byte = hi16*16
  const u16* Ap = A + (size_t)(m0 + wm * 64 + l15) * KDIM + hi16 * 8;

  // stage B 256x32 (16 KB) for K-step t into ring buffer `base`
  // (linear LDS dest, inverse-swizzled global source)
  auto stageB = [&](int t, int base) {
#pragma unroll
    for (int j = 0; j < 2; ++j) {
      int d = (j * 512 + tid) * 16;
      int o = d ^ (((d >> 7) & 3) << 4);   // logical byte: row = o>>6, k-byte = o&63
      gload16(Bb + (size_t)(o >> 6) * KDIM + t * 32 + ((o & 63) >> 1),
              sm + base + d);
    }
  };

  // prologue: tiles 0,1,2 in flight (6 loads/thread); wait tile 0 (allow 4 newer)
  stageB(0, 0);
  stageB(1, 16384);
  stageB(2, 32768);
  VMW(4);
  BAR();

  const int cb = hi16 * 16;   // k-octet byte offset within 64 B row
  const int rbv = wn * 64 + l15;

#pragma unroll 1
  for (int t = 0; t < NKS; ++t) {
    const bool st = (t + 3 < NKS);
    // A frags direct from global (L2-hot); issued BEFORE staging so the
    // compiler's positional vmcnt for aA leaves the 2 staging loads in flight.
#pragma unroll
    for (int mi = 0; mi < 4; ++mi)
      aA[mi] = *(const bf16x8*)(Ap + (size_t)mi * 16 * KDIM + t * 32);
    if (st) stageB(t + 3, ((t + 3) & 3) * 16384);
    const char* cur = sm + (t & 3) * 16384;

    __builtin_amdgcn_s_setprio(1);
#pragma unroll
    for (int h = 0; h < 2; ++h) {
#pragma unroll
      for (int j = 0; j < 2; ++j) bB[j] = frag32(cur, rbv + (h * 2 + j) * 16, cb);
#pragma unroll
      for (int mi = 0; mi < 4; ++mi)
#pragma unroll
        for (int j = 0; j < 2; ++j)
          acc[mi][h * 2 + j] = __builtin_amdgcn_mfma_f32_16x16x32_bf16(
              aA[mi], bB[j], acc[mi][h * 2 + j], 0, 0, 0);
    }
    __builtin_amdgcn_s_setprio(0);
    SCHED();
    if (st) { VMW(4); } else { VMW(0); }   // drain stage(t+1); keep t+2,t+3 in flight
    BAR();
  }

  // ---------------- epilogue: 4 rounds of [128 rows][64 cols] via LDS ----------------
  __syncthreads();
  float* epi = (float*)sm;  // [128][68] = 34816 B
  for (int p = 0; p < 4; ++p) {
    if (p) __syncthreads();
    if (wn == p) {
#pragma unroll
      for (int mi = 0; mi < 4; ++mi)
#pragma unroll
        for (int ni = 0; ni < 4; ++ni)
#pragma unroll
          for (int r = 0; r < 4; ++r)
            epi[(wm * 64 + mi * 16 + hi16 * 4 + r) * 68 + ni * 16 + l15] = acc[mi][ni][r];
    }
    __syncthreads();
    int gcolbase = n0 + p * 64;
#pragma unroll
    for (int i2 = 0; i2 < 4; ++i2) {
      int fidx = i2 * 2048 + tid * 4;
      int row = fidx >> 6, col = fidx & 63;
      f32x4 v = *(const f32x4*)(epi + row * 68 + col);
      int gcol = gcolbase + col;
      const float4 bb = *(const float4*)(bias + gcol);
      v[0] += bb.x; v[1] += bb.y; v[2] += bb.z; v[3] += bb.w;
      __builtin_nontemporal_store(v, (f32x4*)(CoutF + (size_t)(m0 + row) * Ndim + gcol));
    }
  }
}

// ---------------- 128x128 2-phase bf16 MFMA GEMM (layer GEMMs, 2 blocks/CU) ----------------
// EPI 0: U-layer0 (planes 0..3, transform 1,2), bf16 out
// EPI 1: U-layers (planes 0..2), bf16 out
template <int EPI>
__global__ __launch_bounds__(256, 2) void k_gemm128(const u16* __restrict__ A,
                                                    const u16* __restrict__ Bt,
                                                    u16* __restrict__ Cout, int Ndim) {
  extern __shared__ __align__(16) char sm[];   // 65536: buf{0,1} x [A 16K | B 16K]

  int cpx = gridDim.x >> 3;
  int bid = blockIdx.x;
  int wg = (bid & 7) * cpx + (bid >> 3);
  int bm = wg & 31;          // MROWS/128 = 32
  int bn = wg >> 5;
  int m0 = bm * 128, n0 = bn * 128;

  int tid = threadIdx.x;
  int lane = tid & 63, w = tid >> 6;
  int wm = w >> 1, wn = w & 1;           // 2 x 2 waves
  int l15 = lane & 15, hi16 = lane >> 4;
  const int rA = wm * 64 + l15, rB = wn * 64 + l15;

  f32x4 acc[4][4] = {};
  bf16x8 aA[4][2], bB[4][2];

  const u16* Ab = A + (size_t)m0 * KDIM;
  const u16* Bb = Bt + (size_t)n0 * KDIM;

  auto stage_tile = [&](int t, int buf) {
    int base = buf * 32768;
    stage8k(Ab + t * 64,                     sm, base,         tid);
    stage8k(Ab + (size_t)64 * KDIM + t * 64, sm, base + 8192,  tid);
    stage8k(Bb + t * 64,                     sm, base + 16384, tid);
    stage8k(Bb + (size_t)64 * KDIM + t * 64, sm, base + 24576, tid);
  };

  stage_tile(0, 0);
  VMW(0);
  BAR();

#pragma unroll 1
  for (int t = 0; t < NKT; ++t) {
    int cur = (t & 1) * 32768;
    if (t + 1 < NKT) stage_tile(t + 1, (t & 1) ^ 1);
#pragma unroll
    for (int kk = 0; kk < 2; ++kk) {
      int cb = kk * 64 + hi16 * 16;
#pragma unroll
      for (int mi = 0; mi < 4; ++mi) aA[mi][kk] = frag_ld(sm, cur, rA + mi * 16, cb);
#pragma unroll
      for (int ni = 0; ni < 4; ++ni) bB[ni][kk] = frag_ld(sm, cur + 16384, rB + ni * 16, cb);
    }
    __builtin_amdgcn_s_setprio(1);
#pragma unroll
    for (int kk = 0; kk < 2; ++kk)
#pragma unroll
      for (int mi = 0; mi < 4; ++mi)
#pragma unroll
        for (int ni = 0; ni < 4; ++ni)
          acc[mi][ni] = __builtin_amdgcn_mfma_f32_16x16x32_bf16(aA[mi][kk], bB[ni][kk], acc[mi][ni], 0, 0, 0);
    __builtin_amdgcn_s_setprio(0);
    SCHED();
    VMW(0);
    BAR();
  }

  // ---------------- epilogue: 2 rounds of [128 rows][64 cols] via LDS ----------------
  float* epi = (float*)sm;  // [128][68]
  for (int p = 0; p < 2; ++p) {
    if (p) __syncthreads();
    if (wn == p) {
#pragma unroll
      for (int mi = 0; mi < 4; ++mi)
#pragma unroll
        for (int ni = 0; ni < 4; ++ni)
#pragma unroll
          for (int r = 0; r < 4; ++r)
            epi[(wm * 64 + mi * 16 + hi16 * 4 + r) * 68 + ni * 16 + l15] = acc[mi][ni][r];
    }
    __syncthreads();
    int gcolbase = n0 + p * 64;
    int plane = gcolbase >> 10;
#pragma unroll
    for (int i = 0; i < 8; ++i) {
      int fidx = i * 1024 + tid * 4;
      int row = fidx >> 6, col = fidx & 63;
      f32x4 v = *(const f32x4*)(epi + row * 68 + col);
      int gcol = gcolbase + col;
      if (plane == 1) {
#pragma unroll
        for (int j = 0; j < 4; j++) v[j] = -1.44269504f * (v[j] - 3.0f);
      } else if (plane == 2) {
#pragma unroll
        for (int j = 0; j < 4; j++) v[j] = -1.44269504f * v[j];
      }
      u16x4 o;
#pragma unroll
      for (int j = 0; j < 4; j++) o[j] = f2bf(v[j]);
      *(u16x4*)(Cout + (size_t)(m0 + row) * Ndim + gcol) = o;
    }
  }
}

// ---------------- SRU sequential scan (one layer), fused optional transpose ----------------
__global__ __launch_bounds__(256) void k_scan(const u16* __restrict__ U, int P,
                                              const u16* __restrict__ resid, int rstride,
                                              u16* __restrict__ hout,
                                              const float* __restrict__ vc,
                                              const float* __restrict__ hidden,
                                              float* __restrict__ cfin, int layer,
                                              const float* __restrict__ Wsrc,
                                              u16* __restrict__ WtOut, int NdimT) {
  if (blockIdx.x >= NSCAN) {
    transpose_body(blockIdx.x - NSCAN, Wsrc, WtOut, NdimT);
    return;
  }
  if (threadIdx.x >= 64) return;
  int cid = blockIdx.x * 64 + threadIdx.x;  // 0..8191
  int b = cid >> 10, d = cid & 1023;
  float vfp = -1.44269504f * vc[layer * 2048 + d];
  float vrp = -1.44269504f * vc[layer * 2048 + 1024 + d];
  float c = hidden[layer * 8192 + cid];
  const u16* pu = U + (size_t)b * P * 1024 + d;
  const u16* pr = resid + (size_t)b * rstride + d;
  u16* ph = hout + (size_t)b * 1024 + d;
  const int ustep = P * 1024;
  const int rstep = rstride;

  // 16-deep prefetch ring
  u16 su0[16], sa1[16], sa2[16], srs[16];
#pragma unroll
  for (int j = 0; j < 16; j++) {
    su0[j] = pu[(size_t)(8 * j) * ustep];
    sa1[j] = pu[(size_t)(8 * j) * ustep + 1024];
    sa2[j] = pu[(size_t)(8 * j) * ustep + 2048];
    srs[j] = pr[(size_t)(8 * j) * rstep];
  }
  for (int tb = 0; tb < L_SEQ; tb += 16) {
#pragma unroll
    for (int j = 0; j < 16; j++) {
      int t = tb + j;
      float u0f = bf2f(su0[j]), a1f = bf2f(sa1[j]);
      float a2f = bf2f(sa2[j]), rf = bf2f(srs[j]);
      int tp = (t + 16) & 511;
      su0[j] = pu[(size_t)(8 * tp) * ustep];
      sa1[j] = pu[(size_t)(8 * tp) * ustep + 1024];
      sa2[j] = pu[(size_t)(8 * tp) * ustep + 2048];
      srs[j] = pr[(size_t)(8 * tp) * rstep];
      float e1 = __builtin_amdgcn_exp2f(fmaf(vfp, c, a1f));
      float e2 = __builtin_amdgcn_exp2f(fmaf(vrp, c, a2f));
      float fv = __builtin_amdgcn_rcpf(1.0f + e1);
      float rv = __builtin_amdgcn_rcpf(1.0f + e2);
      float cn = fmaf(fv, c - u0f, u0f);
      float hv = fmaf(rv, cn - rf, rf);
      ph[(size_t)t * (BATCH * ND)] = f2bf(hv);
      c = cn;
    }
  }
  cfin[layer * 8192 + cid] = c;
}

extern "C" void kernel_launch(void* const* d_in, const int* in_sizes, int n_in,
                              void* d_out, int out_size, void* d_ws, size_t ws_size,
                              hipStream_t stream) {
  const int*   x      = (const int*)d_in[0];
  const float* hidden = (const float*)d_in[1];
  const float* emb    = (const float*)d_in[2];
  const float* W0     = (const float*)d_in[3];
  const float* Wl     = (const float*)d_in[4];
  const float* vc     = (const float*)d_in[5];
  const float* outW   = (const float*)d_in[6];
  const float* outb   = (const float*)d_in[7];
  float* out = (float*)d_out;

  char* ws = (char*)d_ws;
  u16* hA    = (u16*)ws;                      // 8.4 MB
  u16* hB    = (u16*)(ws + 8388608);          // 8.4 MB
  u16* U     = (u16*)(ws + 16777216);         // 33.5 MB
  u16* Wt    = (u16*)(ws + 50331648);         // 8.4 MB
  float* cfin = out + (size_t)MROWS * VOCAB_N;

  const size_t wtbig_off_big = 58720256;
  bool bigws = ws_size >= (size_t)(wtbig_off_big + (size_t)VOCAB_N * KDIM * 2);
  u16* WtBig = (u16*)(ws + (bigws ? wtbig_off_big : 16777216));  // else aliases U

  // embed + W0 transpose
  k_embed_t<<<2048 + 4096, 256, 0, stream>>>(x, emb, hA, W0, Wt, 4096);

  // ---- layer 0 ----
  k_gemm128<0><<<32 * 32, 256, 65536, stream>>>(hA, Wt, U, 4096);
  k_scan<<<NSCAN + 3072, 256, 0, stream>>>(U, 4, U + 3 * 1024, 4 * 1024, hB, vc, hidden,
                                           cfin, 0, Wl, Wt, 3072);

  // ---- layers 1..3 ----
  const u16* hin[3]  = {hB, hA, hB};
  u16*       hout[3] = {hA, hB, hA};
  for (int l = 1; l <= 3; l++) {
    k_gemm128<1><<<32 * 24, 256, 65536, stream>>>(hin[l - 1], Wt, U, 3072);
    if (l < 3) {
      k_scan<<<NSCAN + 3072, 256, 0, stream>>>(U, 3, hin[l - 1], 1024, hout[l - 1], vc,
                                               hidden, cfin, l,
                                               Wl + (size_t)l * KDIM * 3072, Wt, 3072);
    } else if (bigws) {
      k_scan<<<NSCAN + 32000, 256, 0, stream>>>(U, 3, hin[l - 1], 1024, hout[l - 1], vc,
                                                hidden, cfin, l, outW, WtBig, VOCAB_N);
    } else {
      k_scan<<<NSCAN, 256, 0, stream>>>(U, 3, hin[l - 1], 1024, hout[l - 1], vc,
                                        hidden, cfin, l, nullptr, nullptr, 32);
      k_transpose_cast<<<32000, 256, 0, stream>>>(outW, WtBig, VOCAB_N);
    }
  }

  // ---- output projection: A-direct-from-L2, B 4-deep LDS ring ----
  k_gemm_out<<<32 * 125, 512, 65536, stream>>>(hA, WtBig, out, VOCAB_N, outb);
}

// Round 7
// 657.178 us; speedup vs baseline: 1.4395x; 1.4395x over previous
//
#include <hip/hip_runtime.h>
#include <hip/hip_bf16.h>

#define L_SEQ 512
#define BATCH 8
#define ND 1024
#define VOCAB_N 32000
#define MROWS 4096   // L*B
#define KDIM 1024
#define NKS 32            // KDIM/32 K-steps
#define NSCAN 128

typedef unsigned short u16;
typedef unsigned int u32;
using bf16x8 = __attribute__((ext_vector_type(8))) __bf16;
using f32x4  = __attribute__((ext_vector_type(4))) float;
using u16x8  = __attribute__((ext_vector_type(8))) unsigned short;
using u16x4  = __attribute__((ext_vector_type(4))) unsigned short;

#define BAR() asm volatile("s_barrier" ::: "memory")
#define VMW(n) asm volatile("s_waitcnt vmcnt(" #n ")" ::: "memory")
#define SCHED() __builtin_amdgcn_sched_barrier(0)

static __device__ __forceinline__ u16 f2bf(float f) {
  u32 u = __builtin_bit_cast(u32, f);
  u32 r = u + 0x7FFF + ((u >> 16) & 1);   // RNE
  return (u16)(r >> 16);
}
static __device__ __forceinline__ float bf2f(u16 b) {
  u32 u = ((u32)b) << 16;
  return __builtin_bit_cast(float, u);
}
static __device__ __forceinline__ void gload16(const void* g, void* l) {
  __builtin_amdgcn_global_load_lds(
      (const __attribute__((address_space(1))) void*)g,
      (__attribute__((address_space(3))) void*)l, 16, 0, 0);
}

// shared transpose-block body: 256 threads, 32x32 tile, W f32[K][N] -> Wt bf16[N][K]
static __device__ __forceinline__ void transpose_body(int tb, const float* __restrict__ W,
                                                      u16* __restrict__ Wt, int Ndim) {
  __shared__ float s[32][33];
  int nx = Ndim >> 5;
  int n0 = (tb % nx) * 32, k0 = (tb / nx) * 32;
  int tid = threadIdx.x;
  int tx = tid & 31, ty = tid >> 5;   // 32 x 8
#pragma unroll
  for (int i = 0; i < 4; i++)
    s[ty * 4 + i][tx] = __builtin_nontemporal_load(
        &W[(size_t)(k0 + ty * 4 + i) * Ndim + n0 + tx]);
  __syncthreads();
  int n = tid >> 3, kg = tid & 7;
  u16x4 o;
#pragma unroll
  for (int j = 0; j < 4; j++) o[j] = f2bf(s[kg * 4 + j][n]);
  *(u16x4*)(Wt + (size_t)(n0 + n) * KDIM + k0 + kg * 4) = o;
}

// ---------------- embedding gather + cast, fused with W0 transpose ----------------
__global__ __launch_bounds__(256) void k_embed_t(const int* __restrict__ x,
                                                 const float* __restrict__ emb,
                                                 u16* __restrict__ h,
                                                 const float* __restrict__ Wsrc,
                                                 u16* __restrict__ WtOut, int NdimT) {
  if (blockIdx.x >= 2048) {
    transpose_body(blockIdx.x - 2048, Wsrc, WtOut, NdimT);
    return;
  }
  int t = blockIdx.x * 256 + threadIdx.x;
  int fidx = t * 8;
  int row = fidx >> 10;
  int col = fidx & 1023;
  int tok = x[row];
  const float4* src = (const float4*)(emb + (size_t)tok * ND + col);
  float4 a = src[0], b = src[1];
  u16x8 o;
  o[0]=f2bf(a.x); o[1]=f2bf(a.y); o[2]=f2bf(a.z); o[3]=f2bf(a.w);
  o[4]=f2bf(b.x); o[5]=f2bf(b.y); o[6]=f2bf(b.z); o[7]=f2bf(b.w);
  *(u16x8*)(h + fidx) = o;
}

// ---------------- standalone transpose (fallback path) ----------------
__global__ __launch_bounds__(256) void k_transpose_cast(const float* __restrict__ W,
                                                        u16* __restrict__ Wt, int Ndim) {
  transpose_body(blockIdx.x, W, Wt, Ndim);
}

// BK=32 layout (64 B rows): physical = logical ^ (((o>>7)&3)<<4)
// -> spreads 16 consecutive rows at fixed k-offset over all 8 bank-groups, 2 deep (free).
static __device__ __forceinline__ bf16x8 frag32(const char* smbase, int r, int cb) {
  int p = r * 64 + cb;
  p ^= ((p >> 7) & 3) << 4;
  return *(const bf16x8*)(smbase + p);
}

// ---------------- 128x256 bf16 MFMA GEMM (output projection) ----------------
// 512 threads / 8 waves (2m x 4n), BK=32, triple-buffered LDS (73728 B),
// counted vmcnt(3), 2 blocks/CU. L2-locality work map: XCD x owns bm in
// {4x..4x+3} (1 MB of A, L2-resident) and sweeps bn ascending (bn-major),
// so A staging loads hit L2 and B panels stream HBM->L3 exactly once.
__global__ __launch_bounds__(512, 4) void k_gemm_out(const u16* __restrict__ A,
                                                     const u16* __restrict__ Bt,
                                                     float* __restrict__ CoutF, int Ndim,
                                                     const float* __restrict__ bias) {
  extern __shared__ __align__(16) char sm[];   // 3 x [A 8K | B 16K] = 73728

  int bid = blockIdx.x;
  int xcd = bid & 7;                 // dispatch round-robin across 8 XCDs
  int i = bid >> 3;                  // 0..499 local index within XCD
  int bm = (xcd << 2) | (i & 3);     // XCD owns 4 consecutive A panels (1 MB)
  int bn = i >> 2;                   // bn-major sweep: 4 same-bn blocks concurrent
  int m0 = bm * 128, n0 = bn * 256;

  int tid = threadIdx.x;
  int lane = tid & 63, w = tid >> 6;      // 8 waves
  int wm = w >> 2, wn = w & 3;            // 2 x 4; wave owns rows wm*64+[0,64), cols wn*64+[0,64)
  int l15 = lane & 15, hi16 = lane >> 4;

  f32x4 acc[4][4] = {};
  bf16x8 aA[4], bB[4];

  const u16* Ab = A + (size_t)m0 * KDIM;
  const u16* Bb = Bt + (size_t)n0 * KDIM;

  // stage K-step t into buffer `base` (linear dest, inverse-swizzled global source):
  // A 128x32 (8 KB, 1 load/thread) + B 256x32 (16 KB, 2 loads/thread)
  auto stage = [&](int t, int base) {
    {
      int d = tid * 16;
      int o = d ^ (((d >> 7) & 3) << 4);   // logical byte: row = o>>6, k-byte = o&63
      gload16(Ab + (size_t)(o >> 6) * KDIM + t * 32 + ((o & 63) >> 1), sm + base + d);
    }
#pragma unroll
    for (int j = 0; j < 2; ++j) {
      int d = (j * 512 + tid) * 16;
      int o = d ^ (((d >> 7) & 3) << 4);
      gload16(Bb + (size_t)(o >> 6) * KDIM + t * 32 + ((o & 63) >> 1),
              sm + base + 8192 + d);
    }
  };

  // prologue: tiles 0,1 in flight (6 loads/thread); wait tile 0 (allow tile 1's 3)
  stage(0, 0);
  stage(1, 24576);
  VMW(3);
  BAR();

  const int cb = hi16 * 16;   // k-octet byte offset within 64 B row
  const int ra = wm * 64 + l15;
  const int rbv = wn * 64 + l15;

  int rb = 0, sb = 2;
#pragma unroll 1
  for (int t = 0; t < NKS; ++t) {
    const bool st = (t + 2 < NKS);
    if (st) stage(t + 2, sb * 24576);   // issue early; lands 2 steps ahead
    const char* cur = sm + rb * 24576;
#pragma unroll
    for (int mi = 0; mi < 4; ++mi) aA[mi] = frag32(cur, ra + mi * 16, cb);
#pragma unroll
    for (int ni = 0; ni < 4; ++ni) bB[ni] = frag32(cur + 8192, rbv + ni * 16, cb);
    __builtin_amdgcn_s_setprio(1);
#pragma unroll
    for (int mi = 0; mi < 4; ++mi)
#pragma unroll
      for (int ni = 0; ni < 4; ++ni)
        acc[mi][ni] = __builtin_amdgcn_mfma_f32_16x16x32_bf16(aA[mi], bB[ni], acc[mi][ni], 0, 0, 0);
    __builtin_amdgcn_s_setprio(0);
    SCHED();
    if (st) { VMW(3); } else { VMW(0); }   // tile t+1 landed; t+2 may stay in flight
    BAR();
    rb = (rb == 2) ? 0 : rb + 1;
    sb = (sb == 2) ? 0 : sb + 1;
  }

  // ---------------- epilogue: 4 rounds of [128 rows][64 cols] via LDS ----------------
  float* epi = (float*)sm;  // [128][68]
  for (int p = 0; p < 4; ++p) {
    if (p) __syncthreads();
    if (wn == p) {
#pragma unroll
      for (int mi = 0; mi < 4; ++mi)
#pragma unroll
        for (int ni = 0; ni < 4; ++ni)
#pragma unroll
          for (int r = 0; r < 4; ++r)
            epi[(wm * 64 + mi * 16 + hi16 * 4 + r) * 68 + ni * 16 + l15] = acc[mi][ni][r];
    }
    __syncthreads();
    int gcolbase = n0 + p * 64;
#pragma unroll
    for (int i2 = 0; i2 < 4; ++i2) {
      int fidx = i2 * 2048 + tid * 4;
      int row = fidx >> 6, col = fidx & 63;
      f32x4 v = *(const f32x4*)(epi + row * 68 + col);
      int gcol = gcolbase + col;
      const float4 bb = *(const float4*)(bias + gcol);
      v[0] += bb.x; v[1] += bb.y; v[2] += bb.z; v[3] += bb.w;
      __builtin_nontemporal_store(v, (f32x4*)(CoutF + (size_t)(m0 + row) * Ndim + gcol));
    }
  }
}

// ---------------- 128x128 bf16 MFMA GEMM (layer GEMMs) ----------------
// Rebuilt on the r5 gemm_out structure: BK=32, 3-deep LDS ring (49152 B ->
// 3 blocks/CU, 3 waves/SIMD), counted vmcnt(4) (never 0 mid-loop),
// both-sides BK=32 swizzle, XCD-local A map (bm in {4x..4x+3}, bn-major).
// EPI 0: U-layer0 (planes 0..3, transform 1,2), bf16 out
// EPI 1: U-layers (planes 0..2), bf16 out
template <int EPI>
__global__ __launch_bounds__(256, 3) void k_gemm128(const u16* __restrict__ A,
                                                    const u16* __restrict__ Bt,
                                                    u16* __restrict__ Cout, int Ndim) {
  extern __shared__ __align__(16) char sm[];   // 3 x [A 8K | B 8K] = 49152

  int bid = blockIdx.x;
  int xcd = bid & 7;                 // round-robin across 8 XCDs
  int i = bid >> 3;
  int bm = (xcd << 2) | (i & 3);     // XCD owns 4 consecutive A panels (1 MB, L2-hot)
  int bn = i >> 2;                   // bn-major sweep
  int m0 = bm * 128, n0 = bn * 128;

  int tid = threadIdx.x;
  int lane = tid & 63, w = tid >> 6;
  int wm = w >> 1, wn = w & 1;           // 2 x 2 waves; wave owns 64 x 64
  int l15 = lane & 15, hi16 = lane >> 4;

  f32x4 acc[4][4] = {};
  bf16x8 aA[4], bB[4];

  const u16* Ab = A + (size_t)m0 * KDIM;
  const u16* Bb = Bt + (size_t)n0 * KDIM;

  // stage K-step t: A 128x32 (8 KB) + B 128x32 (8 KB), 4 loads/thread
  auto stage = [&](int t, int base) {
#pragma unroll
    for (int j = 0; j < 2; ++j) {
      int d = (j * 256 + tid) * 16;
      int o = d ^ (((d >> 7) & 3) << 4);   // logical byte: row = o>>6, k-byte = o&63
      gload16(Ab + (size_t)(o >> 6) * KDIM + t * 32 + ((o & 63) >> 1), sm + base + d);
    }
#pragma unroll
    for (int j = 0; j < 2; ++j) {
      int d = (j * 256 + tid) * 16;
      int o = d ^ (((d >> 7) & 3) << 4);
      gload16(Bb + (size_t)(o >> 6) * KDIM + t * 32 + ((o & 63) >> 1),
              sm + base + 8192 + d);
    }
  };

  // prologue: tiles 0,1 in flight (8 loads/thread); wait tile 0 (allow tile 1's 4)
  stage(0, 0);
  stage(1, 16384);
  VMW(4);
  BAR();

  const int cb = hi16 * 16;
  const int ra = wm * 64 + l15;
  const int rbv = wn * 64 + l15;

  int rb = 0, sb = 2;
#pragma unroll 1
  for (int t = 0; t < NKS; ++t) {
    const bool st = (t + 2 < NKS);
    if (st) stage(t + 2, sb * 16384);
    const char* cur = sm + rb * 16384;
#pragma unroll
    for (int mi = 0; mi < 4; ++mi) aA[mi] = frag32(cur, ra + mi * 16, cb);
#pragma unroll
    for (int ni = 0; ni < 4; ++ni) bB[ni] = frag32(cur + 8192, rbv + ni * 16, cb);
    __builtin_amdgcn_s_setprio(1);
#pragma unroll
    for (int mi = 0; mi < 4; ++mi)
#pragma unroll
      for (int ni = 0; ni < 4; ++ni)
        acc[mi][ni] = __builtin_amdgcn_mfma_f32_16x16x32_bf16(aA[mi], bB[ni], acc[mi][ni], 0, 0, 0);
    __builtin_amdgcn_s_setprio(0);
    SCHED();
    if (st) { VMW(4); } else { VMW(0); }   // tile t+1 landed; t+2 stays in flight
    BAR();
    rb = (rb == 2) ? 0 : rb + 1;
    sb = (sb == 2) ? 0 : sb + 1;
  }

  // ---------------- epilogue: 2 rounds of [128 rows][64 cols] via LDS ----------------
  float* epi = (float*)sm;  // [128][68] = 34816 B
  for (int p = 0; p < 2; ++p) {
    if (p) __syncthreads();
    if (wn == p) {
#pragma unroll
      for (int mi = 0; mi < 4; ++mi)
#pragma unroll
        for (int ni = 0; ni < 4; ++ni)
#pragma unroll
          for (int r = 0; r < 4; ++r)
            epi[(wm * 64 + mi * 16 + hi16 * 4 + r) * 68 + ni * 16 + l15] = acc[mi][ni][r];
    }
    __syncthreads();
    int gcolbase = n0 + p * 64;
    int plane = gcolbase >> 10;
#pragma unroll
    for (int i2 = 0; i2 < 8; ++i2) {
      int fidx = i2 * 1024 + tid * 4;
      int row = fidx >> 6, col = fidx & 63;
      f32x4 v = *(const f32x4*)(epi + row * 68 + col);
      int gcol = gcolbase + col;
      if (plane == 1) {
#pragma unroll
        for (int j = 0; j < 4; j++) v[j] = -1.44269504f * (v[j] - 3.0f);
      } else if (plane == 2) {
#pragma unroll
        for (int j = 0; j < 4; j++) v[j] = -1.44269504f * v[j];
      }
      u16x4 o;
#pragma unroll
      for (int j = 0; j < 4; j++) o[j] = f2bf(v[j]);
      *(u16x4*)(Cout + (size_t)(m0 + row) * Ndim + gcol) = o;
    }
  }
}

// ---------------- SRU sequential scan (one layer), fused optional transpose ----------------
__global__ __launch_bounds__(256) void k_scan(const u16* __restrict__ U, int P,
                                              const u16* __restrict__ resid, int rstride,
                                              u16* __restrict__ hout,
                                              const float* __restrict__ vc,
                                              const float* __restrict__ hidden,
                                              float* __restrict__ cfin, int layer,
                                              const float* __restrict__ Wsrc,
                                              u16* __restrict__ WtOut, int NdimT) {
  if (blockIdx.x >= NSCAN) {
    transpose_body(blockIdx.x - NSCAN, Wsrc, WtOut, NdimT);
    return;
  }
  if (threadIdx.x >= 64) return;
  int cid = blockIdx.x * 64 + threadIdx.x;  // 0..8191
  int b = cid >> 10, d = cid & 1023;
  float vfp = -1.44269504f * vc[layer * 2048 + d];
  float vrp = -1.44269504f * vc[layer * 2048 + 1024 + d];
  float c = hidden[layer * 8192 + cid];
  const u16* pu = U + (size_t)b * P * 1024 + d;
  const u16* pr = resid + (size_t)b * rstride + d;
  u16* ph = hout + (size_t)b * 1024 + d;
  const int ustep = P * 1024;
  const int rstep = rstride;

  // 16-deep prefetch ring
  u16 su0[16], sa1[16], sa2[16], srs[16];
#pragma unroll
  for (int j = 0; j < 16; j++) {
    su0[j] = pu[(size_t)(8 * j) * ustep];
    sa1[j] = pu[(size_t)(8 * j) * ustep + 1024];
    sa2[j] = pu[(size_t)(8 * j) * ustep + 2048];
    srs[j] = pr[(size_t)(8 * j) * rstep];
  }
  for (int tb = 0; tb < L_SEQ; tb += 16) {
#pragma unroll
    for (int j = 0; j < 16; j++) {
      int t = tb + j;
      float u0f = bf2f(su0[j]), a1f = bf2f(sa1[j]);
      float a2f = bf2f(sa2[j]), rf = bf2f(srs[j]);
      int tp = (t + 16) & 511;
      su0[j] = pu[(size_t)(8 * tp) * ustep];
      sa1[j] = pu[(size_t)(8 * tp) * ustep + 1024];
      sa2[j] = pu[(size_t)(8 * tp) * ustep + 2048];
      srs[j] = pr[(size_t)(8 * tp) * rstep];
      float e1 = __builtin_amdgcn_exp2f(fmaf(vfp, c, a1f));
      float e2 = __builtin_amdgcn_exp2f(fmaf(vrp, c, a2f));
      float fv = __builtin_amdgcn_rcpf(1.0f + e1);
      float rv = __builtin_amdgcn_rcpf(1.0f + e2);
      float cn = fmaf(fv, c - u0f, u0f);
      float hv = fmaf(rv, cn - rf, rf);
      ph[(size_t)t * (BATCH * ND)] = f2bf(hv);
      c = cn;
    }
  }
  cfin[layer * 8192 + cid] = c;
}

extern "C" void kernel_launch(void* const* d_in, const int* in_sizes, int n_in,
                              void* d_out, int out_size, void* d_ws, size_t ws_size,
                              hipStream_t stream) {
  const int*   x      = (const int*)d_in[0];
  const float* hidden = (const float*)d_in[1];
  const float* emb    = (const float*)d_in[2];
  const float* W0     = (const float*)d_in[3];
  const float* Wl     = (const float*)d_in[4];
  const float* vc     = (const float*)d_in[5];
  const float* outW   = (const float*)d_in[6];
  const float* outb   = (const float*)d_in[7];
  float* out = (float*)d_out;

  char* ws = (char*)d_ws;
  u16* hA    = (u16*)ws;                      // 8.4 MB
  u16* hB    = (u16*)(ws + 8388608);          // 8.4 MB
  u16* U     = (u16*)(ws + 16777216);         // 33.5 MB
  u16* Wt    = (u16*)(ws + 50331648);         // 8.4 MB
  float* cfin = out + (size_t)MROWS * VOCAB_N;

  const size_t wtbig_off_big = 58720256;
  bool bigws = ws_size >= (size_t)(wtbig_off_big + (size_t)VOCAB_N * KDIM * 2);
  u16* WtBig = (u16*)(ws + (bigws ? wtbig_off_big : 16777216));  // else aliases U

  // embed + W0 transpose
  k_embed_t<<<2048 + 4096, 256, 0, stream>>>(x, emb, hA, W0, Wt, 4096);

  // ---- layer 0 ----
  k_gemm128<0><<<32 * 32, 256, 49152, stream>>>(hA, Wt, U, 4096);
  k_scan<<<NSCAN + 3072, 256, 0, stream>>>(U, 4, U + 3 * 1024, 4 * 1024, hB, vc, hidden,
                                           cfin, 0, Wl, Wt, 3072);

  // ---- layers 1..3 ----
  const u16* hin[3]  = {hB, hA, hB};
  u16*       hout[3] = {hA, hB, hA};
  for (int l = 1; l <= 3; l++) {
    k_gemm128<1><<<32 * 24, 256, 49152, stream>>>(hin[l - 1], Wt, U, 3072);
    if (l < 3) {
      k_scan<<<NSCAN + 3072, 256, 0, stream>>>(U, 3, hin[l - 1], 1024, hout[l - 1], vc,
                                               hidden, cfin, l,
                                               Wl + (size_t)l * KDIM * 3072, Wt, 3072);
    } else if (bigws) {
      k_scan<<<NSCAN + 32000, 256, 0, stream>>>(U, 3, hin[l - 1], 1024, hout[l - 1], vc,
                                                hidden, cfin, l, outW, WtBig, VOCAB_N);
    } else {
      k_scan<<<NSCAN, 256, 0, stream>>>(U, 3, hin[l - 1], 1024, hout[l - 1], vc,
                                        hidden, cfin, l, nullptr, nullptr, 32);
      k_transpose_cast<<<32000, 256, 0, stream>>>(outW, WtBig, VOCAB_N);
    }
  }

  // ---- output projection: r5 structure (best known), 2 blocks/CU ----
  k_gemm_out<<<32 * 125, 512, 73728, stream>>>(hA, WtBig, out, VOCAB_N, outb);
}